// Round 1
// baseline (1084.388 us; speedup 1.0000x reference)
//
#include <hip/hip_runtime.h>
#include <math.h>

#define C_IN 32
#define C2C 64
#define HH 256
#define WW 256

#define R2 0.70710678118654752f

// Branchless gelu: erf via Abramowitz-Stegun 7.1.26 (|eps| <= 1.5e-7), hw rcp/exp.
__device__ __forceinline__ float gelu_f(float x) {
    float u = x * R2;
    float a = fabsf(u);
    float t = __builtin_amdgcn_rcpf(fmaf(0.3275911f, a, 1.0f));
    float p = t * fmaf(t, fmaf(t, fmaf(t, fmaf(t, 1.061405429f, -1.453152027f),
                                       1.421413741f), -0.284496736f), 0.254829592f);
    float e = __expf(-a * a);
    float er = fmaf(-p, e, 1.0f);
    er = copysignf(er, u);
    return 0.5f * x * (1.0f + er);
}

// cos/sin(2*pi*l/8) for the inverse-DFT rotation seed (2 loads per thread, once)
__device__ const float CT8d[8] = {1.0f, R2, 0.0f, -R2, -1.0f, -R2, 0.0f, R2};
__device__ const float ST8d[8] = {0.0f, R2, 1.0f, R2, 0.0f, -R2, -1.0f, -R2};

// 8-point real DFT over h with conjugate symmetry: outputs u=0..4 (Ai[0]=Ai[4]=0).
__device__ __forceinline__ void rdft8(const float t[8], float Ar[5], float Ai[5]) {
    float e0 = t[0] + t[4], e1 = t[1] + t[5], e2 = t[2] + t[6], e3 = t[3] + t[7];
    float s04 = t[0] - t[4], s26 = t[2] - t[6];
    float am = t[1] - t[3] - t[5] + t[7];
    float bm = t[1] + t[3] - t[5] - t[7];
    float e02 = e0 + e2, e13 = e1 + e3;
    Ar[0] = e02 + e13;
    Ar[4] = e02 - e13;
    Ar[2] = e0 - e2;
    Ai[2] = e3 - e1;
    float ma = R2 * am, mb = R2 * bm;
    Ar[1] = s04 + ma;
    Ar[3] = s04 - ma;
    Ai[1] = -s26 - mb;
    Ai[3] = s26 - mb;
    Ai[0] = 0.f;
    Ai[4] = 0.f;
}

// write A row (all 8 u, mirrored) into LDS: Ar at c2*76+u*8+w, Ai at +4864
__device__ __forceinline__ void wrA(float* ubuf, int c2x, int l,
                                    const float Ar[5], const float Ai[5]) {
    float* pr = &ubuf[c2x * 76 + l];
    float* pi = &ubuf[4864 + c2x * 76 + l];
    pr[0]  = Ar[0]; pi[0]  = 0.f;
    pr[8]  = Ar[1]; pi[8]  = Ai[1];
    pr[16] = Ar[2]; pi[16] = Ai[2];
    pr[24] = Ar[3]; pi[24] = Ai[3];
    pr[32] = Ar[4]; pi[32] = 0.f;
    pr[40] = Ar[3]; pi[40] = -Ai[3];
    pr[48] = Ar[2]; pi[48] = -Ai[2];
    pr[56] = Ar[1]; pi[56] = -Ai[1];
}

// column DFT (v=0..4) + fft1 * -> gelu -> * fft2
__device__ __forceinline__ void colpass(const float* ubuf, int c2x, int l,
                                        const float* __restrict__ fft1,
                                        const float* __restrict__ fft2,
                                        float gr[5], float gi[5]) {
    constexpr float CT[8] = {1.0f, R2, 0.0f, -R2, -1.0f, -R2, 0.0f, R2};
    constexpr float ST[8] = {0.0f, R2, 1.0f, R2, 0.0f, -R2, -1.0f, -R2};
    float Ar2[8], Ai2[8];
    {
        const float4 r0 = *(const float4*)&ubuf[c2x * 76 + l * 8];
        const float4 r1 = *(const float4*)&ubuf[c2x * 76 + l * 8 + 4];
        const float4 i0 = *(const float4*)&ubuf[4864 + c2x * 76 + l * 8];
        const float4 i1 = *(const float4*)&ubuf[4864 + c2x * 76 + l * 8 + 4];
        Ar2[0] = r0.x; Ar2[1] = r0.y; Ar2[2] = r0.z; Ar2[3] = r0.w;
        Ar2[4] = r1.x; Ar2[5] = r1.y; Ar2[6] = r1.z; Ar2[7] = r1.w;
        Ai2[0] = i0.x; Ai2[1] = i0.y; Ai2[2] = i0.z; Ai2[3] = i0.w;
        Ai2[4] = i1.x; Ai2[5] = i1.y; Ai2[6] = i1.z; Ai2[7] = i1.w;
    }
    #pragma unroll
    for (int v = 0; v < 5; ++v) {
        float fr = 0.f, fi = 0.f;
        #pragma unroll
        for (int w = 0; w < 8; ++w) {
            const int k = (v * w) & 7;
            fr += Ar2[w] * CT[k] + Ai2[w] * ST[k];
            fi += Ai2[w] * CT[k] - Ar2[w] * ST[k];
        }
        const float s1 = fft1[(c2x * 8 + l) * 5 + v];
        const float s2 = fft2[(c2x * 8 + l) * 5 + v];
        gr[v] = gelu_f(fr * s1) * s2;
        gi[v] = gelu_f(fi * s1) * s2;
    }
}

// inverse: row-iDFT over u via rotation recurrence, then column-iDFT (hermitian over v)
__device__ __forceinline__ void invpass(const float* gtab, float c1, float s1, float o[8]) {
    constexpr float CT[8] = {1.0f, R2, 0.0f, -R2, -1.0f, -R2, 0.0f, R2};
    constexpr float ST[8] = {0.0f, R2, 1.0f, R2, 0.0f, -R2, -1.0f, -R2};
    float Rr[5] = {0.f, 0.f, 0.f, 0.f, 0.f};
    float Ri[5] = {0.f, 0.f, 0.f, 0.f, 0.f};
    float cu = 1.f, su = 0.f;
    #pragma unroll
    for (int u = 0; u < 8; ++u) {
        const float4 g0 = *(const float4*)&gtab[u * 12];
        const float4 g1 = *(const float4*)&gtab[u * 12 + 4];
        const float2 g2 = *(const float2*)&gtab[u * 12 + 8];
        Rr[0] += g0.x * cu - g0.y * su;  Ri[0] += g0.x * su + g0.y * cu;
        Rr[1] += g0.z * cu - g0.w * su;  Ri[1] += g0.z * su + g0.w * cu;
        Rr[2] += g1.x * cu - g1.y * su;  Ri[2] += g1.x * su + g1.y * cu;
        Rr[3] += g1.z * cu - g1.w * su;  Ri[3] += g1.z * su + g1.w * cu;
        Rr[4] += g2.x * cu - g2.y * su;  Ri[4] += g2.x * su + g2.y * cu;
        const float nc = cu * c1 - su * s1;
        su = cu * s1 + su * c1;
        cu = nc;
    }
    #pragma unroll
    for (int w = 0; w < 8; ++w) {
        float s = 0.f;
        #pragma unroll
        for (int v = 0; v < 5; ++v) {
            const float m = (v == 0 || v == 4) ? 1.0f : 2.0f;
            const int k = (v * w) & 7;
            s += m * (Rr[v] * CT[k] - Ri[v] * ST[k]);
        }
        o[w] = s * 0.015625f;
    }
}

// ---------------------------------------------------------------------------
// K1: 1x1 conv in (32->64) + per-patch rfft2*fft1 -> gelu -> *fft2 -> irfft2
// 256 threads per patch; thread = (c2 in 0..31 owning {c2, c2+32}, l = 0..7)
// ---------------------------------------------------------------------------
__global__ __launch_bounds__(256, 4)
void k1_spectral(const float* __restrict__ x, const float* __restrict__ w_in,
                 const float* __restrict__ b_in, const float* __restrict__ fft1,
                 const float* __restrict__ fft2, float* __restrict__ z)
{
    // union buffer (38912 B -> 4 blocks/CU):
    //  phase0: xs[c][w][h] at c*100+w*12+h (0..3199); lw2 pairs at 3200+c*66+2*(c2&31)+(c2>>5)
    //  phase1: Ar at c2*76+u*8+w (0..4863); Ai at 4864+...
    //  phase2: g at c2*100+u*12+2v (0..6399)
    __shared__ __align__(16) float ubuf[9728];

    const int tid = threadIdx.x;
    const int c2 = tid >> 3;
    const int l  = tid & 7;

    // XCD-bijective swizzle: each XCD gets one contiguous batch image (1024 blocks)
    int Lf = blockIdx.x + (blockIdx.y << 5) + (blockIdx.z << 10);
    int Lp = ((Lf & 7) << 10) | (Lf >> 3);
    const int b  = Lp >> 10;
    const int hp = (Lp >> 5) & 31;
    const int wp = Lp & 31;
    const int h0 = hp << 3, w0 = wp << 3;

    // ---- stage x patch (f4 global loads) and w_in pairs ----
    #pragma unroll
    for (int k = 0; k < 2; ++k) {
        int i = tid + (k << 8);               // 0..511 float4s
        int c = i >> 4, rem = i & 15;
        int h = rem >> 1, half = rem & 1;
        const float4 v = *(const float4*)&x[((b * C_IN + c) * HH + h0 + h) * WW + w0 + (half << 2)];
        int base = c * 100 + half * 48 + h;
        ubuf[base]      = v.x;
        ubuf[base + 12] = v.y;
        ubuf[base + 24] = v.z;
        ubuf[base + 36] = v.w;
    }
    #pragma unroll
    for (int k = 0; k < 2; ++k) {
        int i = tid + (k << 8);               // 0..511 float4s over w_in
        int ci = i >> 3, c4 = (i & 7) << 2;
        const float4 v = *(const float4*)&w_in[ci * C_IN + c4];
        int col = ((ci & 31) << 1) | (ci >> 5);
        ubuf[3200 + (c4 + 0) * 66 + col] = v.x;
        ubuf[3200 + (c4 + 1) * 66 + col] = v.y;
        ubuf[3200 + (c4 + 2) * 66 + col] = v.z;
        ubuf[3200 + (c4 + 3) * 66 + col] = v.w;
    }
    __syncthreads();

    // ---- 1x1 conv: column w=l, 2 channels per thread ----
    float t0[8], t1[8];
    {
        const float bv0 = b_in[c2], bv1 = b_in[c2 + 32];
        #pragma unroll
        for (int h = 0; h < 8; ++h) { t0[h] = bv0; t1[h] = bv1; }
        #pragma unroll
        for (int c = 0; c < C_IN; ++c) {
            const float2 wv = *(const float2*)&ubuf[3200 + c * 66 + (c2 << 1)];
            const float4 xa = *(const float4*)&ubuf[c * 100 + l * 12];
            const float4 xb = *(const float4*)&ubuf[c * 100 + l * 12 + 4];
            float xv[8];
            xv[0] = xa.x; xv[1] = xa.y; xv[2] = xa.z; xv[3] = xa.w;
            xv[4] = xb.x; xv[5] = xb.y; xv[6] = xb.z; xv[7] = xb.w;
            #pragma unroll
            for (int h = 0; h < 8; ++h) {
                t0[h] = fmaf(wv.x, xv[h], t0[h]);
                t1[h] = fmaf(wv.y, xv[h], t1[h]);
            }
        }
    }

    // ---- row DFT over h (symmetry-reduced) ----
    float Ar_a[5], Ai_a[5], Ar_b[5], Ai_b[5];
    rdft8(t0, Ar_a, Ai_a);
    rdft8(t1, Ar_b, Ai_b);
    __syncthreads();            // xs/lw2 dead -> reuse for A
    wrA(ubuf, c2,      l, Ar_a, Ai_a);
    wrA(ubuf, c2 + 32, l, Ar_b, Ai_b);
    __syncthreads();

    // ---- column DFT + filter + gelu (role u = l) ----
    float gr_a[5], gi_a[5], gr_b[5], gi_b[5];
    colpass(ubuf, c2,      l, fft1, fft2, gr_a, gi_a);
    colpass(ubuf, c2 + 32, l, fft1, fft2, gr_b, gi_b);
    __syncthreads();            // A dead -> reuse for g
    {
        int gb = c2 * 100 + l * 12;
        *(float4*)&ubuf[gb]     = make_float4(gr_a[0], gi_a[0], gr_a[1], gi_a[1]);
        *(float4*)&ubuf[gb + 4] = make_float4(gr_a[2], gi_a[2], gr_a[3], gi_a[3]);
        *(float2*)&ubuf[gb + 8] = make_float2(gr_a[4], gi_a[4]);
        gb = (c2 + 32) * 100 + l * 12;
        *(float4*)&ubuf[gb]     = make_float4(gr_b[0], gi_b[0], gr_b[1], gi_b[1]);
        *(float4*)&ubuf[gb + 4] = make_float4(gr_b[2], gi_b[2], gr_b[3], gi_b[3]);
        *(float2*)&ubuf[gb + 8] = make_float2(gr_b[4], gi_b[4]);
    }
    __syncthreads();

    // ---- inverse (role h = l), rotation recurrence twiddles ----
    const float c1 = CT8d[l], s1 = ST8d[l];
    float o[8];
    invpass(&ubuf[c2 * 100], c1, s1, o);
    {
        float* zp = &z[((b * C2C + c2) * HH + h0 + l) * WW + w0];
        *(float4*)&zp[0] = make_float4(o[0], o[1], o[2], o[3]);
        *(float4*)&zp[4] = make_float4(o[4], o[5], o[6], o[7]);
    }
    invpass(&ubuf[(c2 + 32) * 100], c1, s1, o);
    {
        float* zp = &z[((b * C2C + c2 + 32) * HH + h0 + l) * WW + w0];
        *(float4*)&zp[0] = make_float4(o[0], o[1], o[2], o[3]);
        *(float4*)&zp[4] = make_float4(o[4], o[5], o[6], o[7]);
    }
}

// ---------------------------------------------------------------------------
// K2: 7x7 depthwise conv (pad 3) + gelu + 1x1 conv out (64->32) + bias
// tile 16 wide x 32 tall per 256-thread WG; 8 chunks of 8 channels;
// dw: thread = (c2l = tid>>5, 4x4 output block), aligned b128 LDS reads
// ---------------------------------------------------------------------------
__global__ __launch_bounds__(256, 3)
void k2_dwconv(const float* __restrict__ z, const float* __restrict__ w_dw,
               const float* __restrict__ b_dw, const float* __restrict__ w_out,
               const float* __restrict__ b_out, float* __restrict__ out)
{
    __shared__ __align__(16) float zs[8 * 38 * 28];   // 34048 B, row stride 28 (24 used)
    __shared__ __align__(16) float gbuf[8 * 578];     // 18496 B, row stride 18

    const int tid = threadIdx.x;

    // XCD-bijective swizzle (1024 blocks, one image per XCD)
    int L = blockIdx.x + (blockIdx.y << 4) + (blockIdx.z << 7);
    int Lp = ((L & 7) << 7) | (L >> 3);
    const int b  = Lp >> 7;
    const int ty = (Lp >> 4) & 7;
    const int tx = Lp & 15;
    const int x0g = tx << 4, y0g = ty << 5;

    // dw roles
    const int c2l = tid >> 5;            // 0..7
    const int sub = tid & 31;
    const int sx = sub & 3, sy = sub >> 2;  // 4x4 block at (sx*4, sy*4)

    // fold roles: pixel0 (ox, oy0), pixel1 (ox, oy0+16)
    const int ox = tid & 15, oy0 = tid >> 4;

    float acc0[32], acc1[32];
    #pragma unroll
    for (int c = 0; c < 32; ++c) { const float bv = b_out[c]; acc0[c] = bv; acc1[c] = bv; }

    for (int chunk = 0; chunk < 8; ++chunk) {
        const int cbase = chunk << 3;
        __syncthreads();   // prev chunk's zs/gbuf readers done
        // ---- stage 8 channels, 38x22 halo window (stride 28), zero-padded ----
        for (int i = tid; i < 8 * 38 * 24; i += 256) {
            int cc = i / 912;             // 912 = 38*24
            int r  = i - cc * 912;
            int yy = r / 24;
            int xx = r - yy * 24;
            int gy = y0g - 3 + yy, gx = x0g - 3 + xx;
            float v = 0.f;
            if ((unsigned)gy < HH && (unsigned)gx < WW)
                v = z[((b * C2C + cbase + cc) * HH + gy) * WW + gx];
            zs[cc * 1064 + yy * 28 + xx] = v;
        }
        // per-thread channel weights into registers (uniform per 32-lane group, L2-hot)
        float wd[49];
        {
            const float* wp_ = &w_dw[(cbase + c2l) * 49];
            #pragma unroll
            for (int k = 0; k < 49; ++k) wd[k] = wp_[k];
        }
        const float bd = b_dw[cbase + c2l];
        __syncthreads();

        // ---- depthwise 7x7: 4x4 outputs, sliding 12-wide row window ----
        float a[16];
        #pragma unroll
        for (int i = 0; i < 16; ++i) a[i] = bd;

        const float* zbase = &zs[c2l * 1064 + (sy << 2) * 28 + (sx << 2)];
        #pragma unroll
        for (int ry = 0; ry < 10; ++ry) {
            const float4 f0 = *(const float4*)&zbase[ry * 28];
            const float4 f1 = *(const float4*)&zbase[ry * 28 + 4];
            const float4 f2 = *(const float4*)&zbase[ry * 28 + 8];
            const float f[12] = {f0.x, f0.y, f0.z, f0.w, f1.x, f1.y, f1.z, f1.w,
                                 f2.x, f2.y, f2.z, f2.w};
            #pragma unroll
            for (int i = 0; i < 4; ++i) {
                const int ky = ry - i;
                if (ky >= 0 && ky < 7) {
                    #pragma unroll
                    for (int j = 0; j < 4; ++j) {
                        float s = 0.f;
                        #pragma unroll
                        for (int kx = 0; kx < 7; ++kx)
                            s = fmaf(wd[ky * 7 + kx], f[j + kx], s);
                        a[(i << 2) + j] += s;
                    }
                }
            }
        }
        // ---- gelu + stash ----
        #pragma unroll
        for (int i = 0; i < 4; ++i) {
            const int y = (sy << 2) + i;
            const float g0 = gelu_f(a[(i << 2) + 0]);
            const float g1 = gelu_f(a[(i << 2) + 1]);
            const float g2 = gelu_f(a[(i << 2) + 2]);
            const float g3 = gelu_f(a[(i << 2) + 3]);
            float* gp = &gbuf[c2l * 578 + y * 18 + (sx << 2)];
            *(float2*)&gp[0] = make_float2(g0, g1);
            *(float2*)&gp[2] = make_float2(g2, g3);
        }
        __syncthreads();
        // ---- fold into 32 output-channel accumulators (uniform w_out) ----
        #pragma unroll
        for (int cc = 0; cc < 8; ++cc) {
            const float gv0 = gbuf[cc * 578 + oy0 * 18 + ox];
            const float gv1 = gbuf[cc * 578 + (oy0 + 16) * 18 + ox];
            #pragma unroll
            for (int c = 0; c < 32; ++c) {
                const float wv = w_out[c * C2C + cbase + cc];
                acc0[c] = fmaf(wv, gv0, acc0[c]);
                acc1[c] = fmaf(wv, gv1, acc1[c]);
            }
        }
    }
    #pragma unroll
    for (int c = 0; c < 32; ++c) {
        out[((b * C_IN + c) * HH + y0g + oy0) * WW + x0g + ox]        = acc0[c];
        out[((b * C_IN + c) * HH + y0g + oy0 + 16) * WW + x0g + ox]   = acc1[c];
    }
}

extern "C" void kernel_launch(void* const* d_in, const int* in_sizes, int n_in,
                              void* d_out, int out_size, void* d_ws, size_t ws_size,
                              hipStream_t stream) {
    const float* x     = (const float*)d_in[0];
    const float* w_in  = (const float*)d_in[1];
    const float* b_in  = (const float*)d_in[2];
    const float* fft1  = (const float*)d_in[3];
    const float* fft2  = (const float*)d_in[4];
    const float* w_dw  = (const float*)d_in[5];
    const float* b_dw  = (const float*)d_in[6];
    const float* w_out = (const float*)d_in[7];
    const float* b_out = (const float*)d_in[8];
    float* outp = (float*)d_out;
    float* z = (float*)d_ws;   // 8*64*256*256 fp32 = 128 MiB intermediate

    dim3 g1(32, 32, 8);
    k1_spectral<<<g1, 256, 0, stream>>>(x, w_in, b_in, fft1, fft2, z);
    dim3 g2(16, 8, 8);
    k2_dwconv<<<g2, 256, 0, stream>>>(z, w_dw, b_dw, w_out, b_out, outp);
}

// Round 2
// 401.160 us; speedup vs baseline: 2.7031x; 2.7031x over previous
//
#include <hip/hip_runtime.h>
#include <math.h>

#define C_IN 32
#define C2C 64
#define HH 256
#define WW 256

#define R2 0.70710678118654752f

// Branchless gelu: erf via Abramowitz-Stegun 7.1.26 (|eps| <= 1.5e-7), hw rcp/exp.
__device__ __forceinline__ float gelu_f(float x) {
    float u = x * R2;
    float a = fabsf(u);
    float t = __builtin_amdgcn_rcpf(fmaf(0.3275911f, a, 1.0f));
    float p = t * fmaf(t, fmaf(t, fmaf(t, fmaf(t, 1.061405429f, -1.453152027f),
                                       1.421413741f), -0.284496736f), 0.254829592f);
    float e = __expf(-a * a);
    float er = fmaf(-p, e, 1.0f);
    er = copysignf(er, u);
    return 0.5f * x * (1.0f + er);
}

// cos/sin(2*pi*l/8) for the inverse-DFT rotation seed (2 loads per thread, once)
__device__ const float CT8d[8] = {1.0f, R2, 0.0f, -R2, -1.0f, -R2, 0.0f, R2};
__device__ const float ST8d[8] = {0.0f, R2, 1.0f, R2, 0.0f, -R2, -1.0f, -R2};

// 8-point real DFT over h with conjugate symmetry: outputs u=0..4 (Ai[0]=Ai[4]=0).
__device__ __forceinline__ void rdft8(const float t[8], float Ar[5], float Ai[5]) {
    float e0 = t[0] + t[4], e1 = t[1] + t[5], e2 = t[2] + t[6], e3 = t[3] + t[7];
    float s04 = t[0] - t[4], s26 = t[2] - t[6];
    float am = t[1] - t[3] - t[5] + t[7];
    float bm = t[1] + t[3] - t[5] - t[7];
    float e02 = e0 + e2, e13 = e1 + e3;
    Ar[0] = e02 + e13;
    Ar[4] = e02 - e13;
    Ar[2] = e0 - e2;
    Ai[2] = e3 - e1;
    float ma = R2 * am, mb = R2 * bm;
    Ar[1] = s04 + ma;
    Ar[3] = s04 - ma;
    Ai[1] = -s26 - mb;
    Ai[3] = s26 - mb;
    Ai[0] = 0.f;
    Ai[4] = 0.f;
}

// Store only spectral rows u=0..4 (conjugate symmetry); stride 44 per channel.
// Ar at c2*44 + u*8 + w ; Ai at 2816 + same.
__device__ __forceinline__ void wrA5(float* ubuf, int c2x, int l,
                                     const float Ar[5], const float Ai[5]) {
    float* pr = &ubuf[c2x * 44 + l];
    float* pi = &ubuf[2816 + c2x * 44 + l];
    pr[0]  = Ar[0];  pi[0]  = 0.f;
    pr[8]  = Ar[1];  pi[8]  = Ai[1];
    pr[16] = Ar[2];  pi[16] = Ai[2];
    pr[24] = Ar[3];  pi[24] = Ai[3];
    pr[32] = Ar[4];  pi[32] = 0.f;
}

// column DFT (v=0..4) + fft1 * -> gelu -> * fft2 ; row u=l via A[u]=conj(A[8-u])
__device__ __forceinline__ void colpass(const float* ubuf, int c2x, int l,
                                        const float* __restrict__ fft1,
                                        const float* __restrict__ fft2,
                                        float gr[5], float gi[5]) {
    constexpr float CT[8] = {1.0f, R2, 0.0f, -R2, -1.0f, -R2, 0.0f, R2};
    constexpr float ST[8] = {0.0f, R2, 1.0f, R2, 0.0f, -R2, -1.0f, -R2};
    const int row = (l <= 4) ? l : 8 - l;
    const float sgn = (l <= 4) ? 1.0f : -1.0f;
    float Ar2[8], Ai2[8];
    {
        const float4 r0 = *(const float4*)&ubuf[c2x * 44 + row * 8];
        const float4 r1 = *(const float4*)&ubuf[c2x * 44 + row * 8 + 4];
        const float4 i0 = *(const float4*)&ubuf[2816 + c2x * 44 + row * 8];
        const float4 i1 = *(const float4*)&ubuf[2816 + c2x * 44 + row * 8 + 4];
        Ar2[0] = r0.x; Ar2[1] = r0.y; Ar2[2] = r0.z; Ar2[3] = r0.w;
        Ar2[4] = r1.x; Ar2[5] = r1.y; Ar2[6] = r1.z; Ar2[7] = r1.w;
        Ai2[0] = sgn * i0.x; Ai2[1] = sgn * i0.y; Ai2[2] = sgn * i0.z; Ai2[3] = sgn * i0.w;
        Ai2[4] = sgn * i1.x; Ai2[5] = sgn * i1.y; Ai2[6] = sgn * i1.z; Ai2[7] = sgn * i1.w;
    }
    #pragma unroll
    for (int v = 0; v < 5; ++v) {
        float fr = 0.f, fi = 0.f;
        #pragma unroll
        for (int w = 0; w < 8; ++w) {
            const int k = (v * w) & 7;
            fr += Ar2[w] * CT[k] + Ai2[w] * ST[k];
            fi += Ai2[w] * CT[k] - Ar2[w] * ST[k];
        }
        const float s1 = fft1[(c2x * 8 + l) * 5 + v];
        const float s2 = fft2[(c2x * 8 + l) * 5 + v];
        gr[v] = gelu_f(fr * s1) * s2;
        gi[v] = gelu_f(fi * s1) * s2;
    }
}

// inverse: row-iDFT over u via rotation recurrence, then column-iDFT (hermitian over v)
__device__ __forceinline__ void invpass(const float* gtab, float c1, float s1, float o[8]) {
    constexpr float CT[8] = {1.0f, R2, 0.0f, -R2, -1.0f, -R2, 0.0f, R2};
    constexpr float ST[8] = {0.0f, R2, 1.0f, R2, 0.0f, -R2, -1.0f, -R2};
    float Rr[5] = {0.f, 0.f, 0.f, 0.f, 0.f};
    float Ri[5] = {0.f, 0.f, 0.f, 0.f, 0.f};
    float cu = 1.f, su = 0.f;
    #pragma unroll
    for (int u = 0; u < 8; ++u) {
        const float4 g0 = *(const float4*)&gtab[u * 12];
        const float4 g1 = *(const float4*)&gtab[u * 12 + 4];
        const float2 g2 = *(const float2*)&gtab[u * 12 + 8];
        Rr[0] += g0.x * cu - g0.y * su;  Ri[0] += g0.x * su + g0.y * cu;
        Rr[1] += g0.z * cu - g0.w * su;  Ri[1] += g0.z * su + g0.w * cu;
        Rr[2] += g1.x * cu - g1.y * su;  Ri[2] += g1.x * su + g1.y * cu;
        Rr[3] += g1.z * cu - g1.w * su;  Ri[3] += g1.z * su + g1.w * cu;
        Rr[4] += g2.x * cu - g2.y * su;  Ri[4] += g2.x * su + g2.y * cu;
        const float nc = cu * c1 - su * s1;
        su = cu * s1 + su * c1;
        cu = nc;
    }
    #pragma unroll
    for (int w = 0; w < 8; ++w) {
        float s = 0.f;
        #pragma unroll
        for (int v = 0; v < 5; ++v) {
            const float m = (v == 0 || v == 4) ? 1.0f : 2.0f;
            const int k = (v * w) & 7;
            s += m * (Rr[v] * CT[k] - Ri[v] * ST[k]);
        }
        o[w] = s * 0.015625f;
    }
}

// ---------------------------------------------------------------------------
// K1: 1x1 conv in (32->64) + per-patch rfft2*fft1 -> gelu -> *fft2 -> irfft2
// 256 threads per patch; thread = (c2 in 0..31 owning {c2, c2+32}, l = 0..7)
// ---------------------------------------------------------------------------
__global__ __launch_bounds__(256, 4)
void k1_spectral(const float* __restrict__ x, const float* __restrict__ w_in,
                 const float* __restrict__ b_in, const float* __restrict__ fft1,
                 const float* __restrict__ fft2, float* __restrict__ z)
{
    // union buffer (25600 B -> 6 blocks/CU):
    //  phase0: xs[c][w][h] at c*100+w*12+h (0..3199); lw2 pairs at 3200+c*66+...
    //  phase1: Ar rows 0..4 at c2*44+u*8+w; Ai at 2816+... (0..5631)
    //  phase2: g at c2*100+u*12+2v (0..6399)
    __shared__ __align__(16) float ubuf[6400];

    const int tid = threadIdx.x;
    const int c2 = tid >> 3;
    const int l  = tid & 7;

    // XCD-bijective swizzle: each XCD gets one contiguous batch image (1024 blocks)
    int Lf = blockIdx.x + (blockIdx.y << 5) + (blockIdx.z << 10);
    int Lp = ((Lf & 7) << 10) | (Lf >> 3);
    const int b  = Lp >> 10;
    const int hp = (Lp >> 5) & 31;
    const int wp = Lp & 31;
    const int h0 = hp << 3, w0 = wp << 3;

    // ---- stage x patch (f4 global loads) and w_in pairs ----
    #pragma unroll
    for (int k = 0; k < 2; ++k) {
        int i = tid + (k << 8);               // 0..511 float4s
        int c = i >> 4, rem = i & 15;
        int h = rem >> 1, half = rem & 1;
        const float4 v = *(const float4*)&x[((b * C_IN + c) * HH + h0 + h) * WW + w0 + (half << 2)];
        int base = c * 100 + half * 48 + h;
        ubuf[base]      = v.x;
        ubuf[base + 12] = v.y;
        ubuf[base + 24] = v.z;
        ubuf[base + 36] = v.w;
    }
    #pragma unroll
    for (int k = 0; k < 2; ++k) {
        int i = tid + (k << 8);               // 0..511 float4s over w_in
        int ci = i >> 3, c4 = (i & 7) << 2;
        const float4 v = *(const float4*)&w_in[ci * C_IN + c4];
        int col = ((ci & 31) << 1) | (ci >> 5);
        ubuf[3200 + (c4 + 0) * 66 + col] = v.x;
        ubuf[3200 + (c4 + 1) * 66 + col] = v.y;
        ubuf[3200 + (c4 + 2) * 66 + col] = v.z;
        ubuf[3200 + (c4 + 3) * 66 + col] = v.w;
    }
    __syncthreads();

    // ---- 1x1 conv: column w=l, 2 channels per thread ----
    float t0[8], t1[8];
    {
        const float bv0 = b_in[c2], bv1 = b_in[c2 + 32];
        #pragma unroll
        for (int h = 0; h < 8; ++h) { t0[h] = bv0; t1[h] = bv1; }
        #pragma unroll
        for (int c = 0; c < C_IN; ++c) {
            const float2 wv = *(const float2*)&ubuf[3200 + c * 66 + (c2 << 1)];
            const float4 xa = *(const float4*)&ubuf[c * 100 + l * 12];
            const float4 xb = *(const float4*)&ubuf[c * 100 + l * 12 + 4];
            float xv[8];
            xv[0] = xa.x; xv[1] = xa.y; xv[2] = xa.z; xv[3] = xa.w;
            xv[4] = xb.x; xv[5] = xb.y; xv[6] = xb.z; xv[7] = xb.w;
            #pragma unroll
            for (int h = 0; h < 8; ++h) {
                t0[h] = fmaf(wv.x, xv[h], t0[h]);
                t1[h] = fmaf(wv.y, xv[h], t1[h]);
            }
        }
    }

    // ---- row DFT over h (symmetry-reduced) ----
    float Ar_a[5], Ai_a[5], Ar_b[5], Ai_b[5];
    rdft8(t0, Ar_a, Ai_a);
    rdft8(t1, Ar_b, Ai_b);
    __syncthreads();            // xs/lw2 dead -> reuse for A
    wrA5(ubuf, c2,      l, Ar_a, Ai_a);
    wrA5(ubuf, c2 + 32, l, Ar_b, Ai_b);
    __syncthreads();

    // ---- column DFT + filter + gelu (role u = l) ----
    float gr_a[5], gi_a[5], gr_b[5], gi_b[5];
    colpass(ubuf, c2,      l, fft1, fft2, gr_a, gi_a);
    colpass(ubuf, c2 + 32, l, fft1, fft2, gr_b, gi_b);
    __syncthreads();            // A dead -> reuse for g
    {
        int gb = c2 * 100 + l * 12;
        *(float4*)&ubuf[gb]     = make_float4(gr_a[0], gi_a[0], gr_a[1], gi_a[1]);
        *(float4*)&ubuf[gb + 4] = make_float4(gr_a[2], gi_a[2], gr_a[3], gi_a[3]);
        *(float2*)&ubuf[gb + 8] = make_float2(gr_a[4], gi_a[4]);
        gb = (c2 + 32) * 100 + l * 12;
        *(float4*)&ubuf[gb]     = make_float4(gr_b[0], gi_b[0], gr_b[1], gi_b[1]);
        *(float4*)&ubuf[gb + 4] = make_float4(gr_b[2], gi_b[2], gr_b[3], gi_b[3]);
        *(float2*)&ubuf[gb + 8] = make_float2(gr_b[4], gi_b[4]);
    }
    __syncthreads();

    // ---- inverse (role h = l), rotation recurrence twiddles ----
    const float c1 = CT8d[l], s1 = ST8d[l];
    float o[8];
    invpass(&ubuf[c2 * 100], c1, s1, o);
    {
        float* zp = &z[((b * C2C + c2) * HH + h0 + l) * WW + w0];
        *(float4*)&zp[0] = make_float4(o[0], o[1], o[2], o[3]);
        *(float4*)&zp[4] = make_float4(o[4], o[5], o[6], o[7]);
    }
    invpass(&ubuf[(c2 + 32) * 100], c1, s1, o);
    {
        float* zp = &z[((b * C2C + c2 + 32) * HH + h0 + l) * WW + w0];
        *(float4*)&zp[0] = make_float4(o[0], o[1], o[2], o[3]);
        *(float4*)&zp[4] = make_float4(o[4], o[5], o[6], o[7]);
    }
}

// ---------------------------------------------------------------------------
// K2: 7x7 depthwise conv (pad 3) + gelu + 1x1 conv out (64->32) + bias
// 16x16 tile per 256-thread WG; 16 chunks of 4 channels (one per wave).
// dw: lane = (bx = x-quad, oy = row); 4 outputs via 3 aligned b128 reads/row.
// Weights via wave-uniform readfirstlane pointer -> SGPRs (no VGPR cost).
// ---------------------------------------------------------------------------
__global__ __launch_bounds__(256, 4)
void k2_dwconv(const float* __restrict__ z, const float* __restrict__ w_dw,
               const float* __restrict__ b_dw, const float* __restrict__ w_out,
               const float* __restrict__ b_out, float* __restrict__ out)
{
    __shared__ __align__(16) float zs[4 * 22 * 24];   // 8448 B, stride 24, 24-wide halo
    __shared__ __align__(16) float gbuf[4 * 16 * 24]; // 6144 B, stride 24

    const int tid = threadIdx.x;

    // XCD-bijective swizzle (2048 blocks, one image per XCD)
    int L = blockIdx.x + (blockIdx.y << 4) + (blockIdx.z << 8);
    int Lp = ((L & 7) << 8) | (L >> 3);
    const int b  = Lp >> 8;
    const int ty = (Lp >> 4) & 15;
    const int tx = Lp & 15;
    const int x0g = tx << 4, y0g = ty << 4;

    // dw roles: wave = channel, lane -> (x-quad, output row)
    const int lane = tid & 63;
    const int wv   = tid >> 6;              // 0..3
    const int bx   = lane & 3;              // x block (4 wide)
    const int oy   = lane >> 2;             // 0..15 output row

    // fold / output roles: thread = pixel
    const int ox = tid & 15, py = tid >> 4;

    float acc[32];
    #pragma unroll
    for (int c = 0; c < 32; ++c) acc[c] = b_out[c];

    for (int chunk = 0; chunk < 16; ++chunk) {
        const int cbase = chunk << 2;
        __syncthreads();   // protect zs/gbuf from previous iteration's readers

        // ---- stage 4 channels, 22-row x 24-col halo window (all float4) ----
        // window cols x0g-4 .. x0g+19 (4-aligned); rows y0g-3 .. y0g+18
        for (int i = tid; i < 528; i += 256) {     // 4 ch * 22 rows * 6 f4
            int c2l = i / 132;
            int r   = i - c2l * 132;
            int yy  = r / 6;
            int x4  = r - yy * 6;
            int gy = y0g - 3 + yy;
            int gx = x0g - 4 + (x4 << 2);
            float4 v = make_float4(0.f, 0.f, 0.f, 0.f);
            if ((unsigned)gy < HH && (unsigned)gx < WW)
                v = *(const float4*)&z[((b * C2C + cbase + c2l) * HH + gy) * WW + gx];
            *(float4*)&zs[c2l * 528 + yy * 24 + (x4 << 2)] = v;
        }
        __syncthreads();

        // ---- depthwise 7x7 for channel cbase+wv: 4 outputs per lane ----
        {
            const int c2u = __builtin_amdgcn_readfirstlane(cbase + wv);
            const float* wd = &w_dw[c2u * 49];        // uniform -> s_loads
            const float bd = b_dw[c2u];
            float a0 = bd, a1 = bd, a2 = bd, a3 = bd;
            const float* zb = &zs[wv * 528 + oy * 24 + (bx << 2)];
            #pragma unroll
            for (int ky = 0; ky < 7; ++ky) {
                const float4 q0 = *(const float4*)&zb[ky * 24];
                const float4 q1 = *(const float4*)&zb[ky * 24 + 4];
                const float4 q2 = *(const float4*)&zb[ky * 24 + 8];
                const float fv[11] = {q0.x, q0.y, q0.z, q0.w, q1.x, q1.y, q1.z, q1.w,
                                      q2.x, q2.y, q2.z};
                #pragma unroll
                for (int kx = 0; kx < 7; ++kx) {
                    const float w = wd[ky * 7 + kx];
                    a0 = fmaf(w, fv[kx + 1], a0);
                    a1 = fmaf(w, fv[kx + 2], a1);
                    a2 = fmaf(w, fv[kx + 3], a2);
                    a3 = fmaf(w, fv[kx + 4], a3);
                }
            }
            *(float4*)&gbuf[wv * 384 + oy * 24 + (bx << 2)] =
                make_float4(gelu_f(a0), gelu_f(a1), gelu_f(a2), gelu_f(a3));
        }
        __syncthreads();

        // ---- fold chunk into 32 output-channel accumulators (uniform w_out) ----
        #pragma unroll
        for (int cc = 0; cc < 4; ++cc) {
            const float gv = gbuf[cc * 384 + py * 24 + ox];
            const int c2i = cbase + cc;
            #pragma unroll
            for (int c = 0; c < 32; ++c)
                acc[c] = fmaf(w_out[c * C2C + c2i], gv, acc[c]);
        }
    }

    #pragma unroll
    for (int c = 0; c < 32; ++c)
        out[((b * C_IN + c) * HH + y0g + py) * WW + x0g + ox] = acc[c];
}

extern "C" void kernel_launch(void* const* d_in, const int* in_sizes, int n_in,
                              void* d_out, int out_size, void* d_ws, size_t ws_size,
                              hipStream_t stream) {
    const float* x     = (const float*)d_in[0];
    const float* w_in  = (const float*)d_in[1];
    const float* b_in  = (const float*)d_in[2];
    const float* fft1  = (const float*)d_in[3];
    const float* fft2  = (const float*)d_in[4];
    const float* w_dw  = (const float*)d_in[5];
    const float* b_dw  = (const float*)d_in[6];
    const float* w_out = (const float*)d_in[7];
    const float* b_out = (const float*)d_in[8];
    float* outp = (float*)d_out;
    float* z = (float*)d_ws;   // 8*64*256*256 fp32 = 128 MiB intermediate

    dim3 g1(32, 32, 8);
    k1_spectral<<<g1, 256, 0, stream>>>(x, w_in, b_in, fft1, fft2, z);
    dim3 g2(16, 16, 8);
    k2_dwconv<<<g2, 256, 0, stream>>>(z, w_dw, b_dw, w_out, b_out, outp);
}